// Round 1
// baseline (698.088 us; speedup 1.0000x reference)
//
#include <hip/hip_runtime.h>

#define NF 512
#define NH 3
#define NC 7

// ws layout (floats): [0..63] header (flag int at word 0), [64, 64+N) deg->dis,
// [64+N, 64+4N) xw, [64+4N, 64+7N) agg

__global__ void k_init(float* __restrict__ deg, int* __restrict__ flag, int n) {
    int i = blockIdx.x * blockDim.x + threadIdx.x;
    if (i < n) deg[i] = 1.0f;           // self-loop contribution to degree
    if (i == 0) *flag = 0;
}

// Detect whether edge_index buffer is int64 (odd 32-bit words all zero) or int32.
// Only reads first E 32-bit word-pairs (safe under either dtype).
__global__ void k_detect(const int* __restrict__ ei, int* __restrict__ flag, int E) {
    __shared__ int anynz;
    if (threadIdx.x == 0) anynz = 0;
    __syncthreads();
    int lim = E < 2048 ? E : 2048;
    int nz = 0;
    for (int i = threadIdx.x; i < lim; i += blockDim.x)
        nz |= ei[2 * i + 1];
    if (nz) atomicOr(&anynz, 1);
    __syncthreads();
    if (threadIdx.x == 0) *flag = anynz;   // 1 => int32 layout, 0 => int64 layout
}

__device__ __forceinline__ int load_idx(const void* base, long long i, int is32, long long E) {
    if (is32) return ((const int*)base)[i];
    return (int)((const long long*)base)[i];
}

__global__ void k_deg_count(const void* __restrict__ ei, const int* __restrict__ flag,
                            float* __restrict__ deg, int E, int n) {
    int i = blockIdx.x * blockDim.x + threadIdx.x;
    if (i >= E) return;
    int is32 = *flag;
    // dst row is second row: element offset E within the row-major [2,E] array
    int d = load_idx(ei, (long long)E + i, is32, E);
    if ((unsigned)d < (unsigned)n) atomicAdd(&deg[d], 1.0f);
}

// One wave per row: xw = x @ W_gcn; dis = rsqrt(deg); agg seeded with self-loop msg.
__global__ __launch_bounds__(256) void k_gemm(const float* __restrict__ x,
                                              const float* __restrict__ W,
                                              float* __restrict__ degdis,
                                              float* __restrict__ xw,
                                              float* __restrict__ agg, int n) {
    __shared__ float wl[NF * NH];
    for (int j = threadIdx.x; j < NF * NH; j += 256) wl[j] = W[j];
    __syncthreads();
    int row = blockIdx.x * 4 + (threadIdx.x >> 6);
    if (row >= n) return;
    int lane = threadIdx.x & 63;
    const float4* xp = (const float4*)(x + (size_t)row * NF + lane * 8);
    float4 a = xp[0], b = xp[1];
    float xv[8] = {a.x, a.y, a.z, a.w, b.x, b.y, b.z, b.w};
    float s0 = 0.f, s1 = 0.f, s2 = 0.f;
    int f0 = lane * 8;
#pragma unroll
    for (int j = 0; j < 8; ++j) {
        float v = xv[j];
        const float* wp = &wl[(f0 + j) * NH];
        s0 += v * wp[0];
        s1 += v * wp[1];
        s2 += v * wp[2];
    }
#pragma unroll
    for (int off = 32; off > 0; off >>= 1) {
        s0 += __shfl_down(s0, off);
        s1 += __shfl_down(s1, off);
        s2 += __shfl_down(s2, off);
    }
    if (lane == 0) {
        float d = degdis[row];
        float di = d > 0.f ? rsqrtf(d) : 0.f;
        degdis[row] = di;                 // in-place deg -> d^-1/2
        xw[row * 3 + 0] = s0;
        xw[row * 3 + 1] = s1;
        xw[row * 3 + 2] = s2;
        float n2 = di * di;               // self-loop norm = dis[i]^2
        agg[row * 3 + 0] = s0 * n2;
        agg[row * 3 + 1] = s1 * n2;
        agg[row * 3 + 2] = s2 * n2;
    }
}

__global__ void k_scatter(const void* __restrict__ ei, const int* __restrict__ flag,
                          const float* __restrict__ dis, const float* __restrict__ xw,
                          float* __restrict__ agg, int E, int n) {
    int i = blockIdx.x * blockDim.x + threadIdx.x;
    if (i >= E) return;
    int is32 = *flag;
    int s = load_idx(ei, i, is32, E);
    int d = load_idx(ei, (long long)E + i, is32, E);
    if ((unsigned)s >= (unsigned)n || (unsigned)d >= (unsigned)n) return;
    float w = dis[s] * dis[d];
    atomicAdd(&agg[d * 3 + 0], xw[s * 3 + 0] * w);
    atomicAdd(&agg[d * 3 + 1], xw[s * 3 + 1] * w);
    atomicAdd(&agg[d * 3 + 2], xw[s * 3 + 2] * w);
}

__global__ void k_final(const float* __restrict__ agg, const float* __restrict__ bg,
                        const float* __restrict__ Wo, const float* __restrict__ bo,
                        float* __restrict__ outH, float* __restrict__ outZ, int n) {
    int i = blockIdx.x * blockDim.x + threadIdx.x;
    if (i >= n) return;
    float h0 = fmaxf(agg[i * 3 + 0] + bg[0], 0.f);
    float h1 = fmaxf(agg[i * 3 + 1] + bg[1], 0.f);
    float h2 = fmaxf(agg[i * 3 + 2] + bg[2], 0.f);
    outH[i * 3 + 0] = h0;
    outH[i * 3 + 1] = h1;
    outH[i * 3 + 2] = h2;
#pragma unroll
    for (int c = 0; c < NC; ++c)
        outZ[i * NC + c] = h0 * Wo[0 * NC + c] + h1 * Wo[1 * NC + c] + h2 * Wo[2 * NC + c] + bo[c];
}

extern "C" void kernel_launch(void* const* d_in, const int* in_sizes, int n_in,
                              void* d_out, int out_size, void* d_ws, size_t ws_size,
                              hipStream_t stream) {
    const float* x   = (const float*)d_in[0];
    const void*  ei  = d_in[1];
    const float* Wg  = (const float*)d_in[2];
    const float* bg  = (const float*)d_in[3];
    const float* Wo  = (const float*)d_in[4];
    const float* bo  = (const float*)d_in[5];

    const int N = in_sizes[0] / NF;
    const int E = in_sizes[1] / 2;

    float* ws   = (float*)d_ws;
    int*   flag = (int*)d_ws;
    float* deg  = ws + 64;          // becomes dis in-place
    float* xw   = deg + N;
    float* agg  = xw + (size_t)3 * N;

    float* outH = (float*)d_out;
    float* outZ = outH + (size_t)3 * N;

    dim3 blk(256);
    int gN = (N + 255) / 256;
    int gE = (E + 255) / 256;

    k_init<<<gN, blk, 0, stream>>>(deg, flag, N);
    k_detect<<<1, blk, 0, stream>>>((const int*)ei, flag, E);
    k_deg_count<<<gE, blk, 0, stream>>>(ei, flag, deg, E, N);
    k_gemm<<<(N + 3) / 4, blk, 0, stream>>>(x, Wg, deg, xw, agg, N);
    k_scatter<<<gE, blk, 0, stream>>>(ei, flag, deg, xw, agg, E, N);
    k_final<<<gN, blk, 0, stream>>>(agg, bg, Wo, bo, outH, outZ, N);
}

// Round 2
// 244.655 us; speedup vs baseline: 2.8534x; 2.8534x over previous
//
#include <hip/hip_runtime.h>

#define NF 512
#define NH 3
#define NC 7
#define RB 2048        // rows per dst bucket (power of two)
#define RBS 11         // log2(RB)
#define G1 256         // histogram / sort slice blocks (power of two)
#define SAG 4          // aggregation slices per bucket

// ---------- common ----------

// Detect whether edge_index buffer is int64 (odd 32-bit words all zero) or int32.
__global__ void k_detect(const int* __restrict__ ei, int* __restrict__ flag, int E) {
    __shared__ int anynz;
    if (threadIdx.x == 0) anynz = 0;
    __syncthreads();
    int lim = E < 2048 ? E : 2048;
    int nz = 0;
    for (int i = threadIdx.x; i < lim; i += blockDim.x)
        nz |= ei[2 * i + 1];
    if (nz) atomicOr(&anynz, 1);
    __syncthreads();
    if (threadIdx.x == 0) *flag = anynz;   // 1 => int32 layout, 0 => int64 layout
}

__device__ __forceinline__ int load_idx(const void* base, long long i, int is32) {
    return is32 ? ((const int*)base)[i] : (int)((const long long*)base)[i];
}

// ---------- fast path: counting sort by dst bucket, zero global atomics ----------

__global__ __launch_bounds__(256) void k_hist(const void* __restrict__ ei, const int* __restrict__ flag,
                                              int* __restrict__ hist, int E, int NBv) {
    __shared__ int cnt[64];
    for (int i = threadIdx.x; i < NBv; i += 256) cnt[i] = 0;
    __syncthreads();
    int is32 = *flag;
    int EB = (E + G1 - 1) / G1;
    int e0 = blockIdx.x * EB;
    int e1 = min(E, e0 + EB);
    for (int i = e0 + threadIdx.x; i < e1; i += 256) {
        int d = load_idx(ei, (long long)E + i, is32);
        atomicAdd(&cnt[d >> RBS], 1);
    }
    __syncthreads();
    for (int b = threadIdx.x; b < NBv; b += 256)
        hist[b * G1 + blockIdx.x] = cnt[b];
}

// Exclusive scan of hist[b][g] (bucket-major) -> global write cursors; also bucket start/count.
__global__ __launch_bounds__(1024) void k_scan(int* __restrict__ hist, int* __restrict__ bstart,
                                               int* __restrict__ bcount, int NBv) {
    __shared__ int tot[64], st[64];
    int lane = threadIdx.x & 63;
    int w = threadIdx.x >> 6;                 // 16 waves
    for (int c = w; c < NBv; c += 16) {
        int v[4];
        int base = c * G1 + lane * 4;         // G1==256 -> 4 per lane
#pragma unroll
        for (int j = 0; j < 4; ++j) v[j] = hist[base + j];
        int s = v[0] + v[1] + v[2] + v[3];
        int incl = s;
#pragma unroll
        for (int off = 1; off < 64; off <<= 1) {
            int t = __shfl_up(incl, off);
            if (lane >= off) incl += t;
        }
        int run = incl - s;                   // exclusive
#pragma unroll
        for (int j = 0; j < 4; ++j) { hist[base + j] = run; run += v[j]; }
        int total = __shfl(incl, 63);
        if (lane == 0) tot[c] = total;
    }
    __syncthreads();
    if (threadIdx.x == 0) {
        int run = 0;
        for (int b = 0; b < NBv; ++b) {
            st[b] = run; bstart[b] = run; bcount[b] = tot[b]; run += tot[b];
        }
    }
    __syncthreads();
    for (int i = threadIdx.x; i < NBv * G1; i += 1024)
        hist[i] += st[i >> 8];                // G1==256
}

__global__ __launch_bounds__(256) void k_sort(const void* __restrict__ ei, const int* __restrict__ flag,
                                              const int* __restrict__ hist, unsigned* __restrict__ recs,
                                              int E, int NBv) {
    __shared__ int cur[64];
    for (int b = threadIdx.x; b < NBv; b += 256) cur[b] = hist[b * G1 + blockIdx.x];
    __syncthreads();
    int is32 = *flag;
    int EB = (E + G1 - 1) / G1;
    int e0 = blockIdx.x * EB;
    int e1 = min(E, e0 + EB);
    for (int i = e0 + threadIdx.x; i < e1; i += 256) {
        int s = load_idx(ei, i, is32);
        int d = load_idx(ei, (long long)E + i, is32);
        int b = d >> RBS;
        int pos = atomicAdd(&cur[b], 1);      // LDS cursor only
        recs[pos] = ((unsigned)(d & (RB - 1)) << 17) | (unsigned)s;
    }
}

// Per-bucket in-degree via LDS histogram -> dis = rsqrt(deg+1)
__global__ __launch_bounds__(256) void k_deg(const unsigned* __restrict__ recs,
                                             const int* __restrict__ bstart, const int* __restrict__ bcount,
                                             float* __restrict__ dis, int n) {
    __shared__ int cnt[RB];
    for (int i = threadIdx.x; i < RB; i += 256) cnt[i] = 0;
    __syncthreads();
    int b = blockIdx.x;
    int s0 = bstart[b], s1 = s0 + bcount[b];
    for (int i = s0 + threadIdx.x; i < s1; i += 256)
        atomicAdd(&cnt[recs[i] >> 17], 1);
    __syncthreads();
    int rbase = b << RBS;
    for (int r = threadIdx.x; r < RB; r += 256) {
        int row = rbase + r;
        if (row < n) dis[row] = rsqrtf((float)(cnt[r] + 1));
    }
}

// One wave per row: y = dis[row] * (x @ W_gcn), padded to float4
__global__ __launch_bounds__(256) void k_gemm(const float* __restrict__ x, const float* __restrict__ W,
                                              const float* __restrict__ dis, float* __restrict__ y4, int n) {
    __shared__ float wl[NF * NH];
    for (int j = threadIdx.x; j < NF * NH; j += 256) wl[j] = W[j];
    __syncthreads();
    int row = blockIdx.x * 4 + (threadIdx.x >> 6);
    if (row >= n) return;
    int lane = threadIdx.x & 63;
    const float4* xp = (const float4*)(x + (size_t)row * NF + lane * 8);
    float4 a = xp[0], bb = xp[1];
    float xv[8] = {a.x, a.y, a.z, a.w, bb.x, bb.y, bb.z, bb.w};
    float s0 = 0.f, s1 = 0.f, s2 = 0.f;
    int f0 = lane * 8;
#pragma unroll
    for (int j = 0; j < 8; ++j) {
        float v = xv[j];
        const float* wp = &wl[(f0 + j) * NH];
        s0 += v * wp[0]; s1 += v * wp[1]; s2 += v * wp[2];
    }
#pragma unroll
    for (int off = 32; off; off >>= 1) {
        s0 += __shfl_down(s0, off); s1 += __shfl_down(s1, off); s2 += __shfl_down(s2, off);
    }
    if (lane == 0) {
        float di = dis[row];
        ((float4*)y4)[row] = make_float4(s0 * di, s1 * di, s2 * di, 0.f);
    }
}

// Aggregate u[d] = sum y[src] for bucket slice into LDS, write partial image (no global atomics)
__global__ __launch_bounds__(256) void k_agg(const unsigned* __restrict__ recs,
                                             const int* __restrict__ bstart, const int* __restrict__ bcount,
                                             const float4* __restrict__ y4, float* __restrict__ partial) {
    __shared__ float u[RB * 3];
    for (int i = threadIdx.x; i < RB * 3; i += 256) u[i] = 0.f;
    __syncthreads();
    int b = blockIdx.x / SAG, s = blockIdx.x % SAG;
    int base = bstart[b];
    long long cnt = bcount[b];
    int i0 = base + (int)(cnt * s / SAG);
    int i1 = base + (int)(cnt * (s + 1) / SAG);
    for (int i = i0 + threadIdx.x; i < i1; i += 256) {
        unsigned rec = recs[i];
        int src = rec & 0x1FFFF;
        int r = rec >> 17;
        float4 v = y4[src];
        atomicAdd(&u[r * 3 + 0], v.x);
        atomicAdd(&u[r * 3 + 1], v.y);
        atomicAdd(&u[r * 3 + 2], v.z);
    }
    __syncthreads();
    float4* pp = (float4*)partial + (size_t)blockIdx.x * RB;
    for (int r = threadIdx.x; r < RB; r += 256)
        pp[r] = make_float4(u[r * 3], u[r * 3 + 1], u[r * 3 + 2], 0.f);
}

__global__ __launch_bounds__(256) void k_final(const float* __restrict__ partial, const float4* __restrict__ y4,
                                               const float* __restrict__ dis, const float* __restrict__ bg,
                                               const float* __restrict__ Wo, const float* __restrict__ bo,
                                               float* __restrict__ outH, float* __restrict__ outZ, int n) {
    int i = blockIdx.x * 256 + threadIdx.x;
    if (i >= n) return;
    int b = i >> RBS, r = i & (RB - 1);
    const float4* pp = (const float4*)partial;
    float u0 = 0.f, u1 = 0.f, u2 = 0.f;
#pragma unroll
    for (int s = 0; s < SAG; ++s) {
        float4 v = pp[(size_t)(b * SAG + s) * RB + r];
        u0 += v.x; u1 += v.y; u2 += v.z;
    }
    float4 yv = y4[i];
    float di = dis[i];
    float h0 = fmaxf(di * (u0 + yv.x) + bg[0], 0.f);
    float h1 = fmaxf(di * (u1 + yv.y) + bg[1], 0.f);
    float h2 = fmaxf(di * (u2 + yv.z) + bg[2], 0.f);
    outH[i * 3 + 0] = h0; outH[i * 3 + 1] = h1; outH[i * 3 + 2] = h2;
#pragma unroll
    for (int c = 0; c < NC; ++c)
        outZ[i * NC + c] = h0 * Wo[c] + h1 * Wo[NC + c] + h2 * Wo[2 * NC + c] + bo[c];
}

// ---------- fallback path (round-1 structure, global atomics) ----------

__global__ void k_init_fb(float* deg, int* flag, int n) {
    int i = blockIdx.x * blockDim.x + threadIdx.x;
    if (i < n) deg[i] = 1.0f;
    if (i == 0) *flag = 0;
}
__global__ void k_degc_fb(const void* ei, const int* flag, float* deg, int E, int n) {
    int i = blockIdx.x * blockDim.x + threadIdx.x;
    if (i >= E) return;
    int d = load_idx(ei, (long long)E + i, *flag);
    if ((unsigned)d < (unsigned)n) atomicAdd(&deg[d], 1.0f);
}
__global__ __launch_bounds__(256) void k_gemm_fb(const float* x, const float* W, float* degdis,
                                                 float* xw, float* agg, int n) {
    __shared__ float wl[NF * NH];
    for (int j = threadIdx.x; j < NF * NH; j += 256) wl[j] = W[j];
    __syncthreads();
    int row = blockIdx.x * 4 + (threadIdx.x >> 6);
    if (row >= n) return;
    int lane = threadIdx.x & 63;
    const float4* xp = (const float4*)(x + (size_t)row * NF + lane * 8);
    float4 a = xp[0], b = xp[1];
    float xv[8] = {a.x, a.y, a.z, a.w, b.x, b.y, b.z, b.w};
    float s0 = 0.f, s1 = 0.f, s2 = 0.f;
    int f0 = lane * 8;
#pragma unroll
    for (int j = 0; j < 8; ++j) {
        float v = xv[j];
        const float* wp = &wl[(f0 + j) * NH];
        s0 += v * wp[0]; s1 += v * wp[1]; s2 += v * wp[2];
    }
#pragma unroll
    for (int off = 32; off; off >>= 1) {
        s0 += __shfl_down(s0, off); s1 += __shfl_down(s1, off); s2 += __shfl_down(s2, off);
    }
    if (lane == 0) {
        float d = degdis[row];
        float di = d > 0.f ? rsqrtf(d) : 0.f;
        degdis[row] = di;
        xw[row * 3 + 0] = s0; xw[row * 3 + 1] = s1; xw[row * 3 + 2] = s2;
        float n2 = di * di;
        agg[row * 3 + 0] = s0 * n2; agg[row * 3 + 1] = s1 * n2; agg[row * 3 + 2] = s2 * n2;
    }
}
__global__ void k_scat_fb(const void* ei, const int* flag, const float* dis, const float* xw,
                          float* agg, int E, int n) {
    int i = blockIdx.x * blockDim.x + threadIdx.x;
    if (i >= E) return;
    int is32 = *flag;
    int s = load_idx(ei, i, is32);
    int d = load_idx(ei, (long long)E + i, is32);
    if ((unsigned)s >= (unsigned)n || (unsigned)d >= (unsigned)n) return;
    float w = dis[s] * dis[d];
    atomicAdd(&agg[d * 3 + 0], xw[s * 3 + 0] * w);
    atomicAdd(&agg[d * 3 + 1], xw[s * 3 + 1] * w);
    atomicAdd(&agg[d * 3 + 2], xw[s * 3 + 2] * w);
}
__global__ void k_final_fb(const float* agg, const float* bg, const float* Wo, const float* bo,
                           float* outH, float* outZ, int n) {
    int i = blockIdx.x * blockDim.x + threadIdx.x;
    if (i >= n) return;
    float h0 = fmaxf(agg[i * 3 + 0] + bg[0], 0.f);
    float h1 = fmaxf(agg[i * 3 + 1] + bg[1], 0.f);
    float h2 = fmaxf(agg[i * 3 + 2] + bg[2], 0.f);
    outH[i * 3 + 0] = h0; outH[i * 3 + 1] = h1; outH[i * 3 + 2] = h2;
#pragma unroll
    for (int c = 0; c < NC; ++c)
        outZ[i * NC + c] = h0 * Wo[c] + h1 * Wo[NC + c] + h2 * Wo[2 * NC + c] + bo[c];
}

// ---------- launch ----------

extern "C" void kernel_launch(void* const* d_in, const int* in_sizes, int n_in,
                              void* d_out, int out_size, void* d_ws, size_t ws_size,
                              hipStream_t stream) {
    const float* x  = (const float*)d_in[0];
    const void*  ei = d_in[1];
    const float* Wg = (const float*)d_in[2];
    const float* bg = (const float*)d_in[3];
    const float* Wo = (const float*)d_in[4];
    const float* bo = (const float*)d_in[5];

    const int N = in_sizes[0] / NF;
    const int E = in_sizes[1] / 2;
    const int NBv = (N + RB - 1) >> RBS;

    float* outH = (float*)d_out;
    float* outZ = outH + (size_t)3 * N;

    int*   wsI = (int*)d_ws;
    float* wsF = (float*)d_ws;

    // fast-path ws layout (words)
    size_t off = 64;
    int* flag   = wsI;
    int* hist   = wsI + off; off += (size_t)64 * G1;
    int* bstart = wsI + off; off += 64;
    int* bcount = wsI + off; off += 64;
    float* dis  = wsF + off; off += N;
    off = (off + 3) & ~(size_t)3;
    float* y4   = wsF + off; off += (size_t)4 * N;
    unsigned* recs = (unsigned*)(wsI + off); off += E;
    off = (off + 3) & ~(size_t)3;
    float* partial = wsF + off; off += (size_t)NBv * SAG * RB * 4;

    bool fast = (off * 4 <= ws_size) && (N <= 131072) && (NBv <= 64);

    dim3 blk(256);
    if (fast) {
        k_detect<<<1, blk, 0, stream>>>((const int*)ei, flag, E);
        k_hist<<<G1, blk, 0, stream>>>(ei, flag, hist, E, NBv);
        k_scan<<<1, dim3(1024), 0, stream>>>(hist, bstart, bcount, NBv);
        k_sort<<<G1, blk, 0, stream>>>(ei, flag, hist, recs, E, NBv);
        k_deg<<<NBv, blk, 0, stream>>>(recs, bstart, bcount, dis, N);
        k_gemm<<<(N + 3) / 4, blk, 0, stream>>>(x, Wg, dis, y4, N);
        k_agg<<<NBv * SAG, blk, 0, stream>>>(recs, bstart, bcount, (const float4*)y4, partial);
        k_final<<<(N + 255) / 256, blk, 0, stream>>>(partial, (const float4*)y4, dis, bg, Wo, bo, outH, outZ, N);
    } else {
        float* deg = wsF + 64;
        float* xw  = deg + N;
        float* agg = xw + (size_t)3 * N;
        int gN = (N + 255) / 256, gE = (E + 255) / 256;
        k_init_fb<<<gN, blk, 0, stream>>>(deg, flag, N);
        k_detect<<<1, blk, 0, stream>>>((const int*)ei, flag, E);
        k_degc_fb<<<gE, blk, 0, stream>>>(ei, flag, deg, E, N);
        k_gemm_fb<<<(N + 3) / 4, blk, 0, stream>>>(x, Wg, deg, xw, agg, N);
        k_scat_fb<<<gE, blk, 0, stream>>>(ei, flag, deg, xw, agg, E, N);
        k_final_fb<<<gN, blk, 0, stream>>>(agg, bg, Wo, bo, outH, outZ, N);
    }
}

// Round 3
// 197.333 us; speedup vs baseline: 3.5376x; 1.2398x over previous
//
#include <hip/hip_runtime.h>

#define NF 512
#define NH 3
#define NC 7
#define RB 512         // rows per dst bucket (power of two)
#define RBS 9          // log2(RB)
#define G1 512         // histogram / sort slice blocks (power of two)
#define G1S 9          // log2(G1)
#define VPT (G1 / 64)  // hist values per lane in scan
#define SAG 2          // aggregation slices per bucket
#define NBMAX 256      // max buckets supported by fast path

// ---------- common ----------

// Detect whether edge_index buffer is int64 (odd 32-bit words all zero) or int32.
__global__ void k_detect(const int* __restrict__ ei, int* __restrict__ flag, int E) {
    __shared__ int anynz;
    if (threadIdx.x == 0) anynz = 0;
    __syncthreads();
    int lim = E < 2048 ? E : 2048;
    int nz = 0;
    for (int i = threadIdx.x; i < lim; i += blockDim.x)
        nz |= ei[2 * i + 1];
    if (nz) atomicOr(&anynz, 1);
    __syncthreads();
    if (threadIdx.x == 0) *flag = anynz;   // 1 => int32 layout, 0 => int64 layout
}

__device__ __forceinline__ int load_idx(const void* base, long long i, int is32) {
    return is32 ? ((const int*)base)[i] : (int)((const long long*)base)[i];
}

// ---------- fast path: counting sort by dst bucket, zero global atomics ----------

__global__ __launch_bounds__(256) void k_hist(const void* __restrict__ ei, const int* __restrict__ flag,
                                              int* __restrict__ hist, int E, int NBv) {
    __shared__ int cnt[NBMAX];
    for (int i = threadIdx.x; i < NBv; i += 256) cnt[i] = 0;
    __syncthreads();
    int is32 = *flag;
    int EB = (E + G1 - 1) / G1;
    int e0 = blockIdx.x * EB;
    int e1 = min(E, e0 + EB);
    for (int i = e0 + threadIdx.x; i < e1; i += 256) {
        int d = load_idx(ei, (long long)E + i, is32);
        atomicAdd(&cnt[d >> RBS], 1);
    }
    __syncthreads();
    for (int b = threadIdx.x; b < NBv; b += 256)
        hist[b * G1 + blockIdx.x] = cnt[b];
}

// Exclusive scan of hist[b][g] (bucket-major) -> global write cursors; also bucket start/count.
__global__ __launch_bounds__(1024) void k_scan(int* __restrict__ hist, int* __restrict__ bstart,
                                               int* __restrict__ bcount, int NBv) {
    __shared__ int tot[NBMAX], st[NBMAX];
    int lane = threadIdx.x & 63;
    int w = threadIdx.x >> 6;                 // 16 waves
    for (int c = w; c < NBv; c += 16) {
        int v[VPT];
        int base = c * G1 + lane * VPT;
        int s = 0;
#pragma unroll
        for (int j = 0; j < VPT; ++j) { v[j] = hist[base + j]; s += v[j]; }
        int incl = s;
#pragma unroll
        for (int off = 1; off < 64; off <<= 1) {
            int t = __shfl_up(incl, off);
            if (lane >= off) incl += t;
        }
        int run = incl - s;                   // exclusive within bucket
#pragma unroll
        for (int j = 0; j < VPT; ++j) { hist[base + j] = run; run += v[j]; }
        if (lane == 63) tot[c] = incl;
    }
    __syncthreads();
    if (threadIdx.x == 0) {
        int run = 0;
        for (int b = 0; b < NBv; ++b) {
            st[b] = run; bstart[b] = run; bcount[b] = tot[b]; run += tot[b];
        }
    }
    __syncthreads();
    int tw = NBv * G1;
    for (int i = threadIdx.x; i < tw; i += 1024)
        hist[i] += st[i >> G1S];
}

__global__ __launch_bounds__(256) void k_sort(const void* __restrict__ ei, const int* __restrict__ flag,
                                              const int* __restrict__ hist, unsigned* __restrict__ recs,
                                              int E, int NBv) {
    __shared__ int cur[NBMAX];
    for (int b = threadIdx.x; b < NBv; b += 256) cur[b] = hist[b * G1 + blockIdx.x];
    __syncthreads();
    int is32 = *flag;
    int EB = (E + G1 - 1) / G1;
    int e0 = blockIdx.x * EB;
    int e1 = min(E, e0 + EB);
    for (int i = e0 + threadIdx.x; i < e1; i += 256) {
        int s = load_idx(ei, i, is32);
        int d = load_idx(ei, (long long)E + i, is32);
        int b = d >> RBS;
        int pos = atomicAdd(&cur[b], 1);      // LDS cursor only
        recs[pos] = ((unsigned)(d & (RB - 1)) << 17) | (unsigned)s;
    }
}

// Per-bucket in-degree via LDS histogram -> dis = rsqrt(deg+1)
__global__ __launch_bounds__(256) void k_deg(const unsigned* __restrict__ recs,
                                             const int* __restrict__ bstart, const int* __restrict__ bcount,
                                             float* __restrict__ dis, int n) {
    __shared__ int cnt[RB];
    for (int i = threadIdx.x; i < RB; i += 256) cnt[i] = 0;
    __syncthreads();
    int b = blockIdx.x;
    int s0 = bstart[b], s1 = s0 + bcount[b];
    for (int i = s0 + threadIdx.x; i < s1; i += 256)
        atomicAdd(&cnt[recs[i] >> 17], 1);
    __syncthreads();
    int rbase = b << RBS;
    for (int r = threadIdx.x; r < RB; r += 256) {
        int row = rbase + r;
        if (row < n) dis[row] = rsqrtf((float)(cnt[r] + 1));
    }
}

// Grid-stride, one wave per row, W slice in REGISTERS (no LDS): y = dis[row]*(x@W)
__global__ __launch_bounds__(256) void k_gemm(const float* __restrict__ x, const float* __restrict__ W,
                                              const float* __restrict__ dis, float4* __restrict__ y4,
                                              int n, int nwaves) {
    int lane = threadIdx.x & 63;
    // lane's W slice: rows lane*8..lane*8+7, all 3 cols = 24 floats = 6 float4, contiguous
    float4 w4[6];
    const float4* wp = (const float4*)W;
#pragma unroll
    for (int j = 0; j < 6; ++j) w4[j] = wp[lane * 6 + j];
    const float* wf = (const float*)w4;

    int wid = blockIdx.x * 4 + (threadIdx.x >> 6);
    for (int row = wid; row < n; row += nwaves) {
        const float4* xp = (const float4*)(x + (size_t)row * NF) + lane * 2;
        float4 a = xp[0], b = xp[1];
        float xv[8] = {a.x, a.y, a.z, a.w, b.x, b.y, b.z, b.w};
        float s0 = 0.f, s1 = 0.f, s2 = 0.f;
#pragma unroll
        for (int j = 0; j < 8; ++j) {
            s0 += xv[j] * wf[j * 3 + 0];
            s1 += xv[j] * wf[j * 3 + 1];
            s2 += xv[j] * wf[j * 3 + 2];
        }
#pragma unroll
        for (int off = 32; off; off >>= 1) {
            s0 += __shfl_down(s0, off);
            s1 += __shfl_down(s1, off);
            s2 += __shfl_down(s2, off);
        }
        if (lane == 0) {
            float di = dis[row];
            y4[row] = make_float4(s0 * di, s1 * di, s2 * di, 0.f);
        }
    }
}

// Aggregate u[d] = sum y[src] for bucket slice into LDS, write partial image (no global atomics)
__global__ __launch_bounds__(256) void k_agg(const unsigned* __restrict__ recs,
                                             const int* __restrict__ bstart, const int* __restrict__ bcount,
                                             const float4* __restrict__ y4, float* __restrict__ partial) {
    __shared__ float u[RB * 3];
    for (int i = threadIdx.x; i < RB * 3; i += 256) u[i] = 0.f;
    __syncthreads();
    int b = blockIdx.x / SAG, s = blockIdx.x % SAG;
    int base = bstart[b];
    long long cnt = bcount[b];
    int i0 = base + (int)(cnt * s / SAG);
    int i1 = base + (int)(cnt * (s + 1) / SAG);
    for (int i = i0 + threadIdx.x; i < i1; i += 256) {
        unsigned rec = recs[i];
        int src = rec & 0x1FFFF;
        int r = rec >> 17;
        float4 v = y4[src];
        atomicAdd(&u[r * 3 + 0], v.x);
        atomicAdd(&u[r * 3 + 1], v.y);
        atomicAdd(&u[r * 3 + 2], v.z);
    }
    __syncthreads();
    float4* pp = (float4*)partial + (size_t)blockIdx.x * RB;
    for (int r = threadIdx.x; r < RB; r += 256)
        pp[r] = make_float4(u[r * 3], u[r * 3 + 1], u[r * 3 + 2], 0.f);
}

__global__ __launch_bounds__(256) void k_final(const float* __restrict__ partial, const float4* __restrict__ y4,
                                               const float* __restrict__ dis, const float* __restrict__ bg,
                                               const float* __restrict__ Wo, const float* __restrict__ bo,
                                               float* __restrict__ outH, float* __restrict__ outZ, int n) {
    int i = blockIdx.x * 256 + threadIdx.x;
    if (i >= n) return;
    int b = i >> RBS, r = i & (RB - 1);
    const float4* pp = (const float4*)partial;
    float u0 = 0.f, u1 = 0.f, u2 = 0.f;
#pragma unroll
    for (int s = 0; s < SAG; ++s) {
        float4 v = pp[(size_t)(b * SAG + s) * RB + r];
        u0 += v.x; u1 += v.y; u2 += v.z;
    }
    float4 yv = y4[i];
    float di = dis[i];
    float h0 = fmaxf(di * (u0 + yv.x) + bg[0], 0.f);
    float h1 = fmaxf(di * (u1 + yv.y) + bg[1], 0.f);
    float h2 = fmaxf(di * (u2 + yv.z) + bg[2], 0.f);
    outH[i * 3 + 0] = h0; outH[i * 3 + 1] = h1; outH[i * 3 + 2] = h2;
#pragma unroll
    for (int c = 0; c < NC; ++c)
        outZ[i * NC + c] = h0 * Wo[c] + h1 * Wo[NC + c] + h2 * Wo[2 * NC + c] + bo[c];
}

// ---------- fallback path (round-1 structure, global atomics) ----------

__global__ void k_init_fb(float* deg, int* flag, int n) {
    int i = blockIdx.x * blockDim.x + threadIdx.x;
    if (i < n) deg[i] = 1.0f;
    if (i == 0) *flag = 0;
}
__global__ void k_degc_fb(const void* ei, const int* flag, float* deg, int E, int n) {
    int i = blockIdx.x * blockDim.x + threadIdx.x;
    if (i >= E) return;
    int d = load_idx(ei, (long long)E + i, *flag);
    if ((unsigned)d < (unsigned)n) atomicAdd(&deg[d], 1.0f);
}
__global__ __launch_bounds__(256) void k_gemm_fb(const float* x, const float* W, float* degdis,
                                                 float* xw, float* agg, int n) {
    __shared__ float wl[NF * NH];
    for (int j = threadIdx.x; j < NF * NH; j += 256) wl[j] = W[j];
    __syncthreads();
    int row = blockIdx.x * 4 + (threadIdx.x >> 6);
    if (row >= n) return;
    int lane = threadIdx.x & 63;
    const float4* xp = (const float4*)(x + (size_t)row * NF + lane * 8);
    float4 a = xp[0], b = xp[1];
    float xv[8] = {a.x, a.y, a.z, a.w, b.x, b.y, b.z, b.w};
    float s0 = 0.f, s1 = 0.f, s2 = 0.f;
    int f0 = lane * 8;
#pragma unroll
    for (int j = 0; j < 8; ++j) {
        float v = xv[j];
        const float* wp = &wl[(f0 + j) * NH];
        s0 += v * wp[0]; s1 += v * wp[1]; s2 += v * wp[2];
    }
#pragma unroll
    for (int off = 32; off; off >>= 1) {
        s0 += __shfl_down(s0, off); s1 += __shfl_down(s1, off); s2 += __shfl_down(s2, off);
    }
    if (lane == 0) {
        float d = degdis[row];
        float di = d > 0.f ? rsqrtf(d) : 0.f;
        degdis[row] = di;
        xw[row * 3 + 0] = s0; xw[row * 3 + 1] = s1; xw[row * 3 + 2] = s2;
        float n2 = di * di;
        agg[row * 3 + 0] = s0 * n2; agg[row * 3 + 1] = s1 * n2; agg[row * 3 + 2] = s2 * n2;
    }
}
__global__ void k_scat_fb(const void* ei, const int* flag, const float* dis, const float* xw,
                          float* agg, int E, int n) {
    int i = blockIdx.x * blockDim.x + threadIdx.x;
    if (i >= E) return;
    int is32 = *flag;
    int s = load_idx(ei, i, is32);
    int d = load_idx(ei, (long long)E + i, is32);
    if ((unsigned)s >= (unsigned)n || (unsigned)d >= (unsigned)n) return;
    float w = dis[s] * dis[d];
    atomicAdd(&agg[d * 3 + 0], xw[s * 3 + 0] * w);
    atomicAdd(&agg[d * 3 + 1], xw[s * 3 + 1] * w);
    atomicAdd(&agg[d * 3 + 2], xw[s * 3 + 2] * w);
}
__global__ void k_final_fb(const float* agg, const float* bg, const float* Wo, const float* bo,
                           float* outH, float* outZ, int n) {
    int i = blockIdx.x * blockDim.x + threadIdx.x;
    if (i >= n) return;
    float h0 = fmaxf(agg[i * 3 + 0] + bg[0], 0.f);
    float h1 = fmaxf(agg[i * 3 + 1] + bg[1], 0.f);
    float h2 = fmaxf(agg[i * 3 + 2] + bg[2], 0.f);
    outH[i * 3 + 0] = h0; outH[i * 3 + 1] = h1; outH[i * 3 + 2] = h2;
#pragma unroll
    for (int c = 0; c < NC; ++c)
        outZ[i * NC + c] = h0 * Wo[c] + h1 * Wo[NC + c] + h2 * Wo[2 * NC + c] + bo[c];
}

// ---------- launch ----------

extern "C" void kernel_launch(void* const* d_in, const int* in_sizes, int n_in,
                              void* d_out, int out_size, void* d_ws, size_t ws_size,
                              hipStream_t stream) {
    const float* x  = (const float*)d_in[0];
    const void*  ei = d_in[1];
    const float* Wg = (const float*)d_in[2];
    const float* bg = (const float*)d_in[3];
    const float* Wo = (const float*)d_in[4];
    const float* bo = (const float*)d_in[5];

    const int N = in_sizes[0] / NF;
    const int E = in_sizes[1] / 2;
    const int NBv = (N + RB - 1) >> RBS;

    float* outH = (float*)d_out;
    float* outZ = outH + (size_t)3 * N;

    int*   wsI = (int*)d_ws;
    float* wsF = (float*)d_ws;

    // fast-path ws layout (words)
    size_t off = 64;
    int* flag   = wsI;
    int* hist   = wsI + off; off += (size_t)NBMAX * G1;
    int* bstart = wsI + off; off += NBMAX;
    int* bcount = wsI + off; off += NBMAX;
    float* dis  = wsF + off; off += N;
    off = (off + 3) & ~(size_t)3;
    float* y4   = wsF + off; off += (size_t)4 * N;
    unsigned* recs = (unsigned*)(wsI + off); off += E;
    off = (off + 3) & ~(size_t)3;
    float* partial = wsF + off; off += (size_t)NBv * SAG * RB * 4;

    bool fast = (off * 4 <= ws_size) && (N <= 131072) && (NBv <= NBMAX);

    dim3 blk(256);
    if (fast) {
        k_detect<<<1, blk, 0, stream>>>((const int*)ei, flag, E);
        k_hist<<<G1, blk, 0, stream>>>(ei, flag, hist, E, NBv);
        k_scan<<<1, dim3(1024), 0, stream>>>(hist, bstart, bcount, NBv);
        k_sort<<<G1, blk, 0, stream>>>(ei, flag, hist, recs, E, NBv);
        k_deg<<<NBv, blk, 0, stream>>>(recs, bstart, bcount, dis, N);
        k_gemm<<<2048, blk, 0, stream>>>(x, Wg, dis, (float4*)y4, N, 2048 * 4);
        k_agg<<<NBv * SAG, blk, 0, stream>>>(recs, bstart, bcount, (const float4*)y4, partial);
        k_final<<<(N + 255) / 256, blk, 0, stream>>>(partial, (const float4*)y4, dis, bg, Wo, bo, outH, outZ, N);
    } else {
        float* deg = wsF + 64;
        float* xw  = deg + N;
        float* agg = xw + (size_t)3 * N;
        int gN = (N + 255) / 256, gE = (E + 255) / 256;
        k_init_fb<<<gN, blk, 0, stream>>>(deg, flag, N);
        k_detect<<<1, blk, 0, stream>>>((const int*)ei, flag, E);
        k_degc_fb<<<gE, blk, 0, stream>>>(ei, flag, deg, E, N);
        k_gemm_fb<<<(N + 3) / 4, blk, 0, stream>>>(x, Wg, deg, xw, agg, N);
        k_scat_fb<<<gE, blk, 0, stream>>>(ei, flag, deg, xw, agg, E, N);
        k_final_fb<<<gN, blk, 0, stream>>>(agg, bg, Wo, bo, outH, outZ, N);
    }
}

// Round 4
// 172.683 us; speedup vs baseline: 4.0426x; 1.1427x over previous
//
#include <hip/hip_runtime.h>

#define NF 512
#define NH 3
#define NC 7
#define RB 512         // rows per dst bucket (power of two)
#define RBS 9          // log2(RB)
#define G1 512         // histogram / sort slice blocks (power of two)
#define SAG 4          // aggregation slices per bucket
#define NBMAX 256      // max buckets supported by fast path

// ---------- common ----------

__device__ __forceinline__ int load_idx(const void* base, long long i, int is32) {
    return is32 ? ((const int*)base)[i] : (int)((const long long*)base)[i];
}

// Per-block inline dtype detection: int64 layout has all-odd-words zero over the
// first 2048 pairs; int32 layout (second row = dst values) has nonzero there.
// Deterministic and identical across blocks.
__device__ __forceinline__ int detect_is32(const int* __restrict__ ei, int E, int* anynz) {
    if (threadIdx.x == 0) *anynz = 0;
    __syncthreads();
    int lim = E < 2048 ? E : 2048;
    int nz = 0;
    for (int i = threadIdx.x; i < lim; i += blockDim.x) nz |= ei[2 * i + 1];
    if (nz) atomicOr(anynz, 1);
    __syncthreads();
    return *anynz;
}

// ---------- fast path: counting sort by dst bucket, zero global atomics ----------

__global__ __launch_bounds__(256) void k_hist(const void* __restrict__ ei,
                                              int* __restrict__ hist, int E, int NBv) {
    __shared__ int cnt[NBMAX];
    __shared__ int anynz;
    int is32 = detect_is32((const int*)ei, E, &anynz);
    for (int i = threadIdx.x; i < NBv; i += 256) cnt[i] = 0;
    __syncthreads();
    int EB = (E + G1 - 1) / G1;
    int e0 = blockIdx.x * EB;
    int e1 = min(E, e0 + EB);
    for (int i = e0 + threadIdx.x; i < e1; i += 256) {
        int d = load_idx(ei, (long long)E + i, is32);
        atomicAdd(&cnt[d >> RBS], 1);
    }
    __syncthreads();
    for (int b = threadIdx.x; b < NBv; b += 256)
        hist[b * G1 + blockIdx.x] = cnt[b];
}

// Per-bucket exclusive scan of the G1 per-block counts; emits bucket total.
__global__ __launch_bounds__(512) void k_scanb(int* __restrict__ hist, int* __restrict__ bcount) {
    __shared__ int wsum[8];
    int b = blockIdx.x;
    int t = threadIdx.x, lane = t & 63, w = t >> 6;
    int v = hist[b * G1 + t];
    int incl = v;
#pragma unroll
    for (int off = 1; off < 64; off <<= 1) {
        int tt = __shfl_up(incl, off);
        if (lane >= off) incl += tt;
    }
    if (lane == 63) wsum[w] = incl;
    __syncthreads();
    int p = 0;
    for (int j = 0; j < w; ++j) p += wsum[j];
    hist[b * G1 + t] = p + incl - v;     // bucket-local exclusive
    if (t == 511) bcount[b] = p + incl;  // bucket total
}

// Exclusive scan of bucket totals -> bucket start offsets (one wave).
__global__ __launch_bounds__(64) void k_scano(const int* __restrict__ bcount,
                                              int* __restrict__ bstart, int NBv) {
    int lane = threadIdx.x;
    int v[4];
    int s = 0;
#pragma unroll
    for (int j = 0; j < 4; ++j) {
        int i = lane * 4 + j;
        v[j] = (i < NBv) ? bcount[i] : 0;
        s += v[j];
    }
    int incl = s;
#pragma unroll
    for (int off = 1; off < 64; off <<= 1) {
        int t = __shfl_up(incl, off);
        if (lane >= off) incl += t;
    }
    int run = incl - s;
#pragma unroll
    for (int j = 0; j < 4; ++j) {
        int i = lane * 4 + j;
        if (i < NBv) bstart[i] = run;
        run += v[j];
    }
}

__global__ __launch_bounds__(256) void k_sort(const void* __restrict__ ei,
                                              const int* __restrict__ hist,
                                              const int* __restrict__ bstart,
                                              unsigned* __restrict__ recs, int E, int NBv) {
    __shared__ int cur[NBMAX];
    __shared__ int anynz;
    int is32 = detect_is32((const int*)ei, E, &anynz);
    for (int b = threadIdx.x; b < NBv; b += 256)
        cur[b] = bstart[b] + hist[b * G1 + blockIdx.x];
    __syncthreads();
    int EB = (E + G1 - 1) / G1;
    int e0 = blockIdx.x * EB;
    int e1 = min(E, e0 + EB);
    for (int i = e0 + threadIdx.x; i < e1; i += 256) {
        int s = load_idx(ei, i, is32);
        int d = load_idx(ei, (long long)E + i, is32);
        int b = d >> RBS;
        int pos = atomicAdd(&cur[b], 1);      // LDS cursor only
        recs[pos] = ((unsigned)(d & (RB - 1)) << 17) | (unsigned)s;
    }
}

// Per-bucket in-degree via LDS histogram -> dis = rsqrt(deg+1)
__global__ __launch_bounds__(256) void k_deg(const unsigned* __restrict__ recs,
                                             const int* __restrict__ bstart, const int* __restrict__ bcount,
                                             float* __restrict__ dis, int n) {
    __shared__ int cnt[RB];
    for (int i = threadIdx.x; i < RB; i += 256) cnt[i] = 0;
    __syncthreads();
    int b = blockIdx.x;
    int s0 = bstart[b], s1 = s0 + bcount[b];
    for (int i = s0 + threadIdx.x; i < s1; i += 256)
        atomicAdd(&cnt[recs[i] >> 17], 1);
    __syncthreads();
    int rbase = b << RBS;
    for (int r = threadIdx.x; r < RB; r += 256) {
        int row = rbase + r;
        if (row < n) dis[row] = rsqrtf((float)(cnt[r] + 1));
    }
}

// Grid-stride, one wave per row, W slice in REGISTERS (no LDS): y = dis[row]*(x@W)
__global__ __launch_bounds__(256) void k_gemm(const float* __restrict__ x, const float* __restrict__ W,
                                              const float* __restrict__ dis, float4* __restrict__ y4,
                                              int n, int nwaves) {
    int lane = threadIdx.x & 63;
    float4 w4[6];
    const float4* wp = (const float4*)W;
#pragma unroll
    for (int j = 0; j < 6; ++j) w4[j] = wp[lane * 6 + j];
    const float* wf = (const float*)w4;

    int wid = blockIdx.x * 4 + (threadIdx.x >> 6);
    for (int row = wid; row < n; row += nwaves) {
        const float4* xp = (const float4*)(x + (size_t)row * NF) + lane * 2;
        float4 a = xp[0], b = xp[1];
        float xv[8] = {a.x, a.y, a.z, a.w, b.x, b.y, b.z, b.w};
        float s0 = 0.f, s1 = 0.f, s2 = 0.f;
#pragma unroll
        for (int j = 0; j < 8; ++j) {
            s0 += xv[j] * wf[j * 3 + 0];
            s1 += xv[j] * wf[j * 3 + 1];
            s2 += xv[j] * wf[j * 3 + 2];
        }
#pragma unroll
        for (int off = 32; off; off >>= 1) {
            s0 += __shfl_down(s0, off);
            s1 += __shfl_down(s1, off);
            s2 += __shfl_down(s2, off);
        }
        if (lane == 0) {
            float di = dis[row];
            y4[row] = make_float4(s0 * di, s1 * di, s2 * di, 0.f);
        }
    }
}

// Aggregate u[d] = sum y[src] for bucket slice into LDS, write partial image (no global atomics)
__global__ __launch_bounds__(256) void k_agg(const unsigned* __restrict__ recs,
                                             const int* __restrict__ bstart, const int* __restrict__ bcount,
                                             const float4* __restrict__ y4, float* __restrict__ partial) {
    __shared__ float u[RB * 3];
    for (int i = threadIdx.x; i < RB * 3; i += 256) u[i] = 0.f;
    __syncthreads();
    int b = blockIdx.x / SAG, s = blockIdx.x % SAG;
    int base = bstart[b];
    long long cnt = bcount[b];
    int i0 = base + (int)(cnt * s / SAG);
    int i1 = base + (int)(cnt * (s + 1) / SAG);
    for (int i = i0 + threadIdx.x; i < i1; i += 256) {
        unsigned rec = recs[i];
        int src = rec & 0x1FFFF;
        int r = rec >> 17;
        float4 v = y4[src];
        atomicAdd(&u[r * 3 + 0], v.x);
        atomicAdd(&u[r * 3 + 1], v.y);
        atomicAdd(&u[r * 3 + 2], v.z);
    }
    __syncthreads();
    float4* pp = (float4*)partial + (size_t)blockIdx.x * RB;
    for (int r = threadIdx.x; r < RB; r += 256)
        pp[r] = make_float4(u[r * 3], u[r * 3 + 1], u[r * 3 + 2], 0.f);
}

__global__ __launch_bounds__(256) void k_final(const float* __restrict__ partial, const float4* __restrict__ y4,
                                               const float* __restrict__ dis, const float* __restrict__ bg,
                                               const float* __restrict__ Wo, const float* __restrict__ bo,
                                               float* __restrict__ outH, float* __restrict__ outZ, int n) {
    int i = blockIdx.x * 256 + threadIdx.x;
    if (i >= n) return;
    int b = i >> RBS, r = i & (RB - 1);
    const float4* pp = (const float4*)partial;
    float u0 = 0.f, u1 = 0.f, u2 = 0.f;
#pragma unroll
    for (int s = 0; s < SAG; ++s) {
        float4 v = pp[(size_t)(b * SAG + s) * RB + r];
        u0 += v.x; u1 += v.y; u2 += v.z;
    }
    float4 yv = y4[i];
    float di = dis[i];
    float h0 = fmaxf(di * (u0 + yv.x) + bg[0], 0.f);
    float h1 = fmaxf(di * (u1 + yv.y) + bg[1], 0.f);
    float h2 = fmaxf(di * (u2 + yv.z) + bg[2], 0.f);
    outH[i * 3 + 0] = h0; outH[i * 3 + 1] = h1; outH[i * 3 + 2] = h2;
#pragma unroll
    for (int c = 0; c < NC; ++c)
        outZ[i * NC + c] = h0 * Wo[c] + h1 * Wo[NC + c] + h2 * Wo[2 * NC + c] + bo[c];
}

// ---------- fallback path (round-1 structure, global atomics) ----------

__global__ void k_detect_fb(const int* ei, int* flag, int E) {
    __shared__ int anynz;
    if (threadIdx.x == 0) anynz = 0;
    __syncthreads();
    int lim = E < 2048 ? E : 2048;
    int nz = 0;
    for (int i = threadIdx.x; i < lim; i += blockDim.x) nz |= ei[2 * i + 1];
    if (nz) atomicOr(&anynz, 1);
    __syncthreads();
    if (threadIdx.x == 0) *flag = anynz;
}
__global__ void k_init_fb(float* deg, int n) {
    int i = blockIdx.x * blockDim.x + threadIdx.x;
    if (i < n) deg[i] = 1.0f;
}
__global__ void k_degc_fb(const void* ei, const int* flag, float* deg, int E, int n) {
    int i = blockIdx.x * blockDim.x + threadIdx.x;
    if (i >= E) return;
    int d = load_idx(ei, (long long)E + i, *flag);
    if ((unsigned)d < (unsigned)n) atomicAdd(&deg[d], 1.0f);
}
__global__ __launch_bounds__(256) void k_gemm_fb(const float* x, const float* W, float* degdis,
                                                 float* xw, float* agg, int n) {
    __shared__ float wl[NF * NH];
    for (int j = threadIdx.x; j < NF * NH; j += 256) wl[j] = W[j];
    __syncthreads();
    int row = blockIdx.x * 4 + (threadIdx.x >> 6);
    if (row >= n) return;
    int lane = threadIdx.x & 63;
    const float4* xp = (const float4*)(x + (size_t)row * NF + lane * 8);
    float4 a = xp[0], b = xp[1];
    float xv[8] = {a.x, a.y, a.z, a.w, b.x, b.y, b.z, b.w};
    float s0 = 0.f, s1 = 0.f, s2 = 0.f;
    int f0 = lane * 8;
#pragma unroll
    for (int j = 0; j < 8; ++j) {
        float v = xv[j];
        const float* wp = &wl[(f0 + j) * NH];
        s0 += v * wp[0]; s1 += v * wp[1]; s2 += v * wp[2];
    }
#pragma unroll
    for (int off = 32; off; off >>= 1) {
        s0 += __shfl_down(s0, off); s1 += __shfl_down(s1, off); s2 += __shfl_down(s2, off);
    }
    if (lane == 0) {
        float d = degdis[row];
        float di = d > 0.f ? rsqrtf(d) : 0.f;
        degdis[row] = di;
        xw[row * 3 + 0] = s0; xw[row * 3 + 1] = s1; xw[row * 3 + 2] = s2;
        float n2 = di * di;
        agg[row * 3 + 0] = s0 * n2; agg[row * 3 + 1] = s1 * n2; agg[row * 3 + 2] = s2 * n2;
    }
}
__global__ void k_scat_fb(const void* ei, const int* flag, const float* dis, const float* xw,
                          float* agg, int E, int n) {
    int i = blockIdx.x * blockDim.x + threadIdx.x;
    if (i >= E) return;
    int is32 = *flag;
    int s = load_idx(ei, i, is32);
    int d = load_idx(ei, (long long)E + i, is32);
    if ((unsigned)s >= (unsigned)n || (unsigned)d >= (unsigned)n) return;
    float w = dis[s] * dis[d];
    atomicAdd(&agg[d * 3 + 0], xw[s * 3 + 0] * w);
    atomicAdd(&agg[d * 3 + 1], xw[s * 3 + 1] * w);
    atomicAdd(&agg[d * 3 + 2], xw[s * 3 + 2] * w);
}
__global__ void k_final_fb(const float* agg, const float* bg, const float* Wo, const float* bo,
                           float* outH, float* outZ, int n) {
    int i = blockIdx.x * blockDim.x + threadIdx.x;
    if (i >= n) return;
    float h0 = fmaxf(agg[i * 3 + 0] + bg[0], 0.f);
    float h1 = fmaxf(agg[i * 3 + 1] + bg[1], 0.f);
    float h2 = fmaxf(agg[i * 3 + 2] + bg[2], 0.f);
    outH[i * 3 + 0] = h0; outH[i * 3 + 1] = h1; outH[i * 3 + 2] = h2;
#pragma unroll
    for (int c = 0; c < NC; ++c)
        outZ[i * NC + c] = h0 * Wo[c] + h1 * Wo[NC + c] + h2 * Wo[2 * NC + c] + bo[c];
}

// ---------- launch ----------

extern "C" void kernel_launch(void* const* d_in, const int* in_sizes, int n_in,
                              void* d_out, int out_size, void* d_ws, size_t ws_size,
                              hipStream_t stream) {
    const float* x  = (const float*)d_in[0];
    const void*  ei = d_in[1];
    const float* Wg = (const float*)d_in[2];
    const float* bg = (const float*)d_in[3];
    const float* Wo = (const float*)d_in[4];
    const float* bo = (const float*)d_in[5];

    const int N = in_sizes[0] / NF;
    const int E = in_sizes[1] / 2;
    const int NBv = (N + RB - 1) >> RBS;

    float* outH = (float*)d_out;
    float* outZ = outH + (size_t)3 * N;

    int*   wsI = (int*)d_ws;
    float* wsF = (float*)d_ws;

    // fast-path ws layout (words)
    size_t off = 64;
    int* hist   = wsI + off; off += (size_t)NBMAX * G1;
    int* bstart = wsI + off; off += NBMAX;
    int* bcount = wsI + off; off += NBMAX;
    float* dis  = wsF + off; off += N;
    off = (off + 3) & ~(size_t)3;
    float* y4   = wsF + off; off += (size_t)4 * N;
    unsigned* recs = (unsigned*)(wsI + off); off += E;
    off = (off + 3) & ~(size_t)3;
    float* partial = wsF + off; off += (size_t)NBv * SAG * RB * 4;

    bool fast = (off * 4 <= ws_size) && (N <= 131072) && (NBv <= NBMAX);

    dim3 blk(256);
    if (fast) {
        k_hist<<<G1, blk, 0, stream>>>(ei, hist, E, NBv);
        k_scanb<<<NBv, dim3(512), 0, stream>>>(hist, bcount);
        k_scano<<<1, dim3(64), 0, stream>>>(bcount, bstart, NBv);
        k_sort<<<G1, blk, 0, stream>>>(ei, hist, bstart, recs, E, NBv);
        k_deg<<<NBv, blk, 0, stream>>>(recs, bstart, bcount, dis, N);
        k_gemm<<<2048, blk, 0, stream>>>(x, Wg, dis, (float4*)y4, N, 2048 * 4);
        k_agg<<<NBv * SAG, blk, 0, stream>>>(recs, bstart, bcount, (const float4*)y4, partial);
        k_final<<<(N + 255) / 256, blk, 0, stream>>>(partial, (const float4*)y4, dis, bg, Wo, bo, outH, outZ, N);
    } else {
        int* flag  = wsI;
        float* deg = wsF + 64;
        float* xw  = deg + N;
        float* agg = xw + (size_t)3 * N;
        int gN = (N + 255) / 256, gE = (E + 255) / 256;
        k_detect_fb<<<1, blk, 0, stream>>>((const int*)ei, flag, E);
        k_init_fb<<<gN, blk, 0, stream>>>(deg, N);
        k_degc_fb<<<gE, blk, 0, stream>>>(ei, flag, deg, E, N);
        k_gemm_fb<<<(N + 3) / 4, blk, 0, stream>>>(x, Wg, deg, xw, agg, N);
        k_scat_fb<<<gE, blk, 0, stream>>>(ei, flag, deg, xw, agg, E, N);
        k_final_fb<<<gN, blk, 0, stream>>>(agg, bg, Wo, bo, outH, outZ, N);
    }
}